// Round 7
// baseline (485.105 us; speedup 1.0000x reference)
//
#include <hip/hip_runtime.h>
#include <hip/hip_fp16.h>

#define DIM 128
#define NGRAPH 512
#define BUCKET_SHIFT 9
#define BUCKET_NODES 512
#define AGG_NODES 128   // nodes per aggregate block
#define AGG_MAXE 4096   // staged edges per aggregate block

typedef _Float16 half8 __attribute__((ext_vector_type(8)));
typedef float floatx4 __attribute__((ext_vector_type(4)));

// ---------- per-block int64-layout detection (ei values random -> unambiguous) ----------
__device__ __forceinline__ int detect64(const int* __restrict__ ei) {
  int all0 = 1;
#pragma unroll
  for (int k = 0; k < 32; ++k) all0 &= (ei[2 * k + 1] == 0);
  return all0;
}

__device__ __forceinline__ int edge_at(const int* p, long long idx, int is64) {
  return is64 ? p[idx * 2] : p[(size_t)idx];
}

// ---------- bucket histogram ----------
__global__ __launch_bounds__(256) void k_bucket_hist(const int* __restrict__ ei, int E,
                                                     int* __restrict__ bucket_count,
                                                     int nbuck) {
  __shared__ int h[256];
  int tid = threadIdx.x;
  h[tid] = 0;
  __syncthreads();
  int is64 = detect64(ei);
  int half = E >> 1;
  if (is64) {
    const int4* dp = (const int4*)(ei + 2 * (size_t)E);
    for (int t = blockIdx.x * 256 + tid; t < half; t += gridDim.x * 256) {
      int4 d = dp[t];
      atomicAdd(&h[d.x >> BUCKET_SHIFT], 1);
      atomicAdd(&h[d.z >> BUCKET_SHIFT], 1);
    }
  } else {
    const int2* dp = (const int2*)(ei + (size_t)E);
    for (int t = blockIdx.x * 256 + tid; t < half; t += gridDim.x * 256) {
      int2 d = dp[t];
      atomicAdd(&h[d.x >> BUCKET_SHIFT], 1);
      atomicAdd(&h[d.y >> BUCKET_SHIFT], 1);
    }
  }
  __syncthreads();
  if (tid < nbuck && h[tid]) atomicAdd(&bucket_count[tid], h[tid]);
  if ((E & 1) && blockIdx.x == 0 && tid == 0) {
    int d = edge_at(ei, (long long)E + (E - 1), is64);
    atomicAdd(&bucket_count[d >> BUCKET_SHIFT], 1);
  }
}

// ---------- scan buckets (1 block) ----------
__global__ __launch_bounds__(256) void k_bucket_scan(const int* __restrict__ bucket_count,
                                                     int* __restrict__ bucket_off,
                                                     int* __restrict__ bucket_cursor,
                                                     int* __restrict__ row_off,
                                                     int nbuck, int N, int E) {
  __shared__ int s[256];
  int t = threadIdx.x;
  int v = (t < nbuck) ? bucket_count[t] : 0;
  s[t] = v;
  __syncthreads();
  for (int off = 1; off < 256; off <<= 1) {
    int u = (t >= off) ? s[t - off] : 0;
    __syncthreads();
    s[t] += u;
    __syncthreads();
  }
  int excl = s[t] - v;
  if (t < nbuck) { bucket_off[t] = excl; bucket_cursor[t] = excl; }
  if (t == 0) { bucket_off[nbuck] = E; row_off[N] = E; }
}

// ---------- scatter edges into bucket-grouped staging ----------
__global__ __launch_bounds__(256) void k_scatter(const int* __restrict__ ei, int E,
                                                 int* __restrict__ flag,
                                                 int* __restrict__ bucket_cursor,
                                                 int2* __restrict__ staging, int nbuck) {
  __shared__ int h[256];
  __shared__ int basebuf[256];
  int tid = threadIdx.x;
  int half = E >> 1;
  int ppb = (half + gridDim.x - 1) / gridDim.x;
  int lo = blockIdx.x * ppb;
  int hi = min(lo + ppb, half);
  h[tid] = 0;
  __syncthreads();
  int is64 = detect64(ei);
  if (blockIdx.x == 0 && tid == 0) *flag = is64;  // published for k_pool_partial
  if (is64) {
    const int4* dp = (const int4*)(ei + 2 * (size_t)E);
    for (int t = lo + tid; t < hi; t += 256) {
      int4 d = dp[t];
      atomicAdd(&h[d.x >> BUCKET_SHIFT], 1);
      atomicAdd(&h[d.z >> BUCKET_SHIFT], 1);
    }
  } else {
    const int2* dp = (const int2*)(ei + (size_t)E);
    for (int t = lo + tid; t < hi; t += 256) {
      int2 d = dp[t];
      atomicAdd(&h[d.x >> BUCKET_SHIFT], 1);
      atomicAdd(&h[d.y >> BUCKET_SHIFT], 1);
    }
  }
  __syncthreads();
  if (tid < nbuck) {
    int c = h[tid];
    if (c) basebuf[tid] = atomicAdd(&bucket_cursor[tid], c);
    h[tid] = 0;  // reuse as local cursor
  }
  __syncthreads();
  if (is64) {
    const int4* sp = (const int4*)ei;
    const int4* dp = (const int4*)(ei + 2 * (size_t)E);
    for (int t = lo + tid; t < hi; t += 256) {
      int4 sv = sp[t];
      int4 dv = dp[t];
      int b0 = dv.x >> BUCKET_SHIFT;
      int l0 = atomicAdd(&h[b0], 1);
      staging[basebuf[b0] + l0] = make_int2(sv.x, dv.x);
      int b1 = dv.z >> BUCKET_SHIFT;
      int l1 = atomicAdd(&h[b1], 1);
      staging[basebuf[b1] + l1] = make_int2(sv.z, dv.z);
    }
  } else {
    const int2* sp = (const int2*)ei;
    const int2* dp = (const int2*)(ei + (size_t)E);
    for (int t = lo + tid; t < hi; t += 256) {
      int2 sv = sp[t];
      int2 dv = dp[t];
      int b0 = dv.x >> BUCKET_SHIFT;
      int l0 = atomicAdd(&h[b0], 1);
      staging[basebuf[b0] + l0] = make_int2(sv.x, dv.x);
      int b1 = dv.y >> BUCKET_SHIFT;
      int l1 = atomicAdd(&h[b1], 1);
      staging[basebuf[b1] + l1] = make_int2(sv.y, dv.y);
    }
  }
  if ((E & 1) && blockIdx.x == 0 && tid == 0) {
    int s0 = edge_at(ei, E - 1, is64);
    int d0 = edge_at(ei, (long long)E + (E - 1), is64);
    int pos = atomicAdd(&bucket_cursor[d0 >> BUCKET_SHIFT], 1);
    staging[pos] = make_int2(s0, d0);
  }
}

// ---------- per-bucket CSR build ----------
__global__ __launch_bounds__(256) void k_csr_build(const int2* __restrict__ staging,
                                                   const int* __restrict__ bucket_off,
                                                   int* __restrict__ row_off,
                                                   float* __restrict__ dinv,
                                                   int* __restrict__ csr_src, int N) {
  __shared__ int cnt_s[BUCKET_NODES];
  __shared__ int s[256];
  int tid = threadIdx.x;
  int b = blockIdx.x;
  int base = b << BUCKET_SHIFT;
  cnt_s[tid] = 0;
  cnt_s[tid + 256] = 0;
  __syncthreads();
  int start = bucket_off[b], end = bucket_off[b + 1];
  for (int i = start + tid; i < end; i += 256) {
    int2 e = staging[i];
    atomicAdd(&cnt_s[e.y - base], 1);
  }
  __syncthreads();
  int a0 = cnt_s[2 * tid], a1 = cnt_s[2 * tid + 1];
  int ps = a0 + a1;
  s[tid] = ps;
  __syncthreads();
  for (int off = 1; off < 256; off <<= 1) {
    int u = (tid >= off) ? s[tid - off] : 0;
    __syncthreads();
    s[tid] += u;
    __syncthreads();
  }
  int excl = s[tid] - ps;
  int r0 = start + excl;
  int r1 = r0 + a0;
  cnt_s[2 * tid] = r0;
  cnt_s[2 * tid + 1] = r1;
  int n0 = base + 2 * tid, n1 = n0 + 1;
  if (n0 < N) { row_off[n0] = r0; dinv[n0] = rsqrtf((float)(a0 + 1)); }
  if (n1 < N) { row_off[n1] = r1; dinv[n1] = rsqrtf((float)(a1 + 1)); }
  __syncthreads();
  for (int i = start + tid; i < end; i += 256) {
    int2 e = staging[i];
    int pos = atomicAdd(&cnt_s[e.y - base], 1);
    csr_src[pos] = e.x;
  }
}

// ---------- MFMA split-fp16 GEMM: Yb[slice][row][16] = fp16( dinv .* (A @ W) ) ----------
// Yb is feature-slice-blocked: slice s (16 dims) of row n lives at Yb + (s*N + n)*16.
#define OTS 136  // OT row stride in halves (pad: 272 B -> <=2-way LDS bank aliasing)
__global__ __launch_bounds__(256) void k_gemm_mfma(
    const float* __restrict__ A, const float* __restrict__ W,
    const float* __restrict__ dinv, __half* __restrict__ Yb, int M) {
  __shared__ _Float16 WH[16384];          // [s][c][lane][8] : 32 KB
  __shared__ _Float16 WL[16384];          // residuals      : 32 KB
  __shared__ _Float16 OT[4][16 * OTS];    // per-wave out tile (padded)
  int tid = threadIdx.x;

  for (int idx = tid; idx < 2048; idx += 256) {
    int l = idx & 63, c = (idx >> 6) & 7, s = idx >> 9;
    int kbase = s * 32 + ((l >> 4) << 3);
    int col = c * 16 + (l & 15);
#pragma unroll
    for (int j = 0; j < 8; ++j) {
      float w = W[(kbase + j) * 128 + col];
      _Float16 hh = (_Float16)w;
      WH[idx * 8 + j] = hh;
      WL[idx * 8 + j] = (_Float16)(w - (float)hh);
    }
  }
  __syncthreads();

  int wid = tid >> 6, l = tid & 63;
  int row0 = blockIdx.x * 64 + wid * 16;
  int arow = row0 + (l & 15);
  if (arow >= M) arow = M - 1;

  floatx4 acc[8];
#pragma unroll
  for (int c = 0; c < 8; ++c) acc[c] = (floatx4){0.f, 0.f, 0.f, 0.f};

#pragma unroll
  for (int s = 0; s < 4; ++s) {
    const float* ap = &A[(size_t)arow * 128 + s * 32 + ((l >> 4) << 3)];
    float4 f0 = *(const float4*)ap;
    float4 f1 = *(const float4*)(ap + 4);
    float fv[8] = {f0.x, f0.y, f0.z, f0.w, f1.x, f1.y, f1.z, f1.w};
    half8 ah, alo;
#pragma unroll
    for (int j = 0; j < 8; ++j) {
      _Float16 hh = (_Float16)fv[j];
      ah[j] = hh;
      alo[j] = (_Float16)(fv[j] - (float)hh);
    }
#pragma unroll
    for (int c = 0; c < 8; ++c) {
      int fi = ((s * 8 + c) * 64 + l) * 8;
      half8 bh = *(half8*)&WH[fi];
      half8 bl8 = *(half8*)&WL[fi];
      acc[c] = __builtin_amdgcn_mfma_f32_16x16x32_f16(ah, bh, acc[c], 0, 0, 0);
      acc[c] = __builtin_amdgcn_mfma_f32_16x16x32_f16(alo, bh, acc[c], 0, 0, 0);
      acc[c] = __builtin_amdgcn_mfma_f32_16x16x32_f16(ah, bl8, acc[c], 0, 0, 0);
    }
  }

  _Float16* ot = &OT[wid][0];
  int lrb = (l >> 4) * 4;
  float dv[4];
#pragma unroll
  for (int r = 0; r < 4; ++r) {
    int gr = row0 + lrb + r;
    dv[r] = (gr < M) ? dinv[gr] : 0.f;
  }
#pragma unroll
  for (int c = 0; c < 8; ++c)
#pragma unroll
    for (int r = 0; r < 4; ++r)
      ot[(lrb + r) * OTS + c * 16 + (l & 15)] = (_Float16)(acc[c][r] * dv[r]);
  // sliced write-out: idx = q*64+l; row = idx&15 (consecutive lanes -> consecutive
  // rows, 512 B-contiguous global runs); piece = idx>>4 -> slice = piece>>1.
#pragma unroll
  for (int q = 0; q < 4; ++q) {
    int idx = q * 64 + l;
    int row = idx & 15;
    int piece = idx >> 4;
    int slice = piece >> 1, hp = piece & 1;
    int grow = row0 + row;
    float4 v = *(const float4*)&ot[row * OTS + piece * 8];
    if (grow < M)
      *(float4*)&Yb[((size_t)slice * M + grow) * 16 + hp * 8] = v;
  }
}

// ---------- aggregation (slice-blocked): block = (chunk of 128 nodes) x slice ----------
// out[n][s*16..] = dinv_n * (sum_e Yb[s][src] + Yb[s][n]) + b[s*16..]
__global__ __launch_bounds__(256) void k_aggregate(
    const __half* __restrict__ Yb, const int* __restrict__ csr_src,
    const int* __restrict__ row_off, const float* __restrict__ dinv,
    const float* __restrict__ bias, float* __restrict__ out, int do_relu, int N) {
  __shared__ int sidx[AGG_MAXE];
  __shared__ int srow[AGG_NODES + 1];
  int tid = threadIdx.x;
  int slice = blockIdx.x & 7;           // consecutive blocks -> different XCDs
  int chunk = blockIdx.x >> 3;
  int n0 = chunk * AGG_NODES;
  if (tid <= AGG_NODES) srow[tid] = row_off[min(n0 + tid, N)];
  __syncthreads();
  int blockBeg = srow[0];
  int len = srow[AGG_NODES] - blockBeg;
  int nload = min(len, AGG_MAXE);
  for (int t = tid; t < nload; t += 256) sidx[t] = csr_src[blockBeg + t];
  __syncthreads();

  int p = tid >> 1;                     // pair id = local node
  int plane = tid & 1;                  // half of the 32 B slice chunk
  int node = n0 + p;
  if (node >= N) return;
  int beg = srow[p] - blockBeg, end = srow[p + 1] - blockBeg;
  const float4* ybase = (const float4*)(Yb + (size_t)slice * N * 16);
  float a0 = 0.f, a1 = 0.f, a2 = 0.f, a3 = 0.f, a4 = 0.f, a5 = 0.f, a6 = 0.f, a7 = 0.f;
#define ACC8(F4)                                                        \
  {                                                                     \
    float4 _f = (F4);                                                   \
    __half2 _h0 = *(__half2*)&_f.x, _h1 = *(__half2*)&_f.y;             \
    __half2 _h2 = *(__half2*)&_f.z, _h3 = *(__half2*)&_f.w;             \
    a0 += __low2float(_h0); a1 += __high2float(_h0);                    \
    a2 += __low2float(_h1); a3 += __high2float(_h1);                    \
    a4 += __low2float(_h2); a5 += __high2float(_h2);                    \
    a6 += __low2float(_h3); a7 += __high2float(_h3);                    \
  }
  int e = beg;
  if (len <= AGG_MAXE) {
    for (; e + 8 <= end; e += 8) {
      int i0 = sidx[e + 0], i1 = sidx[e + 1], i2 = sidx[e + 2], i3 = sidx[e + 3];
      int i4 = sidx[e + 4], i5 = sidx[e + 5], i6 = sidx[e + 6], i7 = sidx[e + 7];
      float4 v0 = ybase[(size_t)i0 * 2 + plane];
      float4 v1 = ybase[(size_t)i1 * 2 + plane];
      float4 v2 = ybase[(size_t)i2 * 2 + plane];
      float4 v3 = ybase[(size_t)i3 * 2 + plane];
      float4 v4 = ybase[(size_t)i4 * 2 + plane];
      float4 v5 = ybase[(size_t)i5 * 2 + plane];
      float4 v6 = ybase[(size_t)i6 * 2 + plane];
      float4 v7 = ybase[(size_t)i7 * 2 + plane];
      ACC8(v0) ACC8(v1) ACC8(v2) ACC8(v3) ACC8(v4) ACC8(v5) ACC8(v6) ACC8(v7)
    }
    for (; e < end; ++e) ACC8(ybase[(size_t)sidx[e] * 2 + plane]);
  } else {
    for (; e < end; ++e) ACC8(ybase[(size_t)csr_src[blockBeg + e] * 2 + plane]);
  }
  ACC8(ybase[(size_t)node * 2 + plane]);  // self loop
#undef ACC8
  float di = dinv[node];
  const float* bp = &bias[slice * 16 + plane * 8];
  float4 o0, o1;
  o0.x = di * a0 + bp[0]; o0.y = di * a1 + bp[1];
  o0.z = di * a2 + bp[2]; o0.w = di * a3 + bp[3];
  o1.x = di * a4 + bp[4]; o1.y = di * a5 + bp[5];
  o1.z = di * a6 + bp[6]; o1.w = di * a7 + bp[7];
  if (do_relu) {
    o0.x = fmaxf(o0.x, 0.f); o0.y = fmaxf(o0.y, 0.f);
    o0.z = fmaxf(o0.z, 0.f); o0.w = fmaxf(o0.w, 0.f);
    o1.x = fmaxf(o1.x, 0.f); o1.y = fmaxf(o1.y, 0.f);
    o1.z = fmaxf(o1.z, 0.f); o1.w = fmaxf(o1.w, 0.f);
  }
  float* op = &out[(size_t)node * 128 + slice * 16 + plane * 8];
  *(float4*)op = o0;
  *(float4*)(op + 4) = o1;
}

// ---------- parallel mean-pool partial ----------
__global__ __launch_bounds__(128) void k_pool_partial(
    const float* __restrict__ h, const int* __restrict__ batch,
    float* __restrict__ pooled, int* __restrict__ pcnt, int n,
    const int* __restrict__ flag) {
  __shared__ int sbatch[128];
  int tid = threadIdx.x;
  int n0 = blockIdx.x * 128;
  int n1 = min(n0 + 128, n);
  int cnt = n1 - n0;
  int is64 = *flag;
  if (tid < cnt) sbatch[tid] = is64 ? batch[2 * (n0 + tid)] : batch[n0 + tid];
  __syncthreads();
  float acc = 0.f;
  int gcur = sbatch[0];
  int runlen = 0;
  for (int r = 0; r < cnt; ++r) {
    int g = sbatch[r];
    if (g != gcur) {
      atomicAdd(&pooled[(size_t)gcur * 128 + tid], acc);
      if (tid == 0) atomicAdd(&pcnt[gcur], runlen);
      acc = 0.f; runlen = 0; gcur = g;
    }
    acc += h[(size_t)(n0 + r) * 128 + tid];
    ++runlen;
  }
  atomicAdd(&pooled[(size_t)gcur * 128 + tid], acc);
  if (tid == 0) atomicAdd(&pcnt[gcur], runlen);
}

// ---------- finish: mean + relu + [512x128]@[128x32] + bl ----------
__global__ __launch_bounds__(256) void k_final2(
    const float* __restrict__ pooled, const int* __restrict__ pcnt,
    const float* __restrict__ Wl, const float* __restrict__ bl,
    float* __restrict__ out) {
  __shared__ float sW[128 * 32];
  __shared__ float sg[8][128];
  int tid = threadIdx.x;
  for (int t = tid; t < 128 * 32; t += 256) sW[t] = Wl[t];
  int r = blockIdx.x * 8 + (tid >> 5);  // graph id
  int c = tid & 31;
  float inv = 1.f / fmaxf((float)pcnt[r], 1.f);
#pragma unroll
  for (int q = 0; q < 4; ++q)
    sg[tid >> 5][c * 4 + q] = fmaxf(pooled[(size_t)r * 128 + c * 4 + q] * inv, 0.f);
  __syncthreads();
  const float* g = sg[tid >> 5];
  float acc = bl[c];
#pragma unroll 8
  for (int k = 0; k < 128; ++k) acc += g[k] * sW[k * 32 + c];
  out[r * 32 + c] = acc;
}

extern "C" void kernel_launch(void* const* d_in, const int* in_sizes, int n_in,
                              void* d_out, int out_size, void* d_ws, size_t ws_size,
                              hipStream_t stream) {
  const float* x   = (const float*)d_in[0];
  const int* ei    = (const int*)d_in[1];
  const int* batch = (const int*)d_in[2];
  const float* W1  = (const float*)d_in[3];
  const float* b1  = (const float*)d_in[4];
  const float* W2  = (const float*)d_in[5];
  const float* b2  = (const float*)d_in[6];
  const float* Wl  = (const float*)d_in[7];
  const float* bl  = (const float*)d_in[8];
  float* out = (float*)d_out;

  const int N = in_sizes[0] / DIM;   // 100000
  const int E = in_sizes[1] / 2;     // 1600000
  const int NBUCK = (N + BUCKET_NODES - 1) >> BUCKET_SHIFT;  // 196

  size_t need = (size_t)N * DIM * 2 + (size_t)N * DIM * 4 + (size_t)E * 4
              + (size_t)(N + 1) * 4 + (size_t)N * 4 + 3 * 1088 + 64
              + (size_t)NGRAPH * DIM * 4 + NGRAPH * 4;
  if (ws_size < need) return;

  char* w = (char*)d_ws;
  __half* bufY  = (__half*)w; w += (size_t)N * DIM * 2;   // slice-blocked
  float* bufH   = (float*)w;  w += (size_t)N * DIM * 4;
  int* csr_src  = (int*)w;    w += (size_t)E * 4;
  int* row_off  = (int*)w;    w += (size_t)(N + 1) * 4;
  float* dinv   = (float*)w;  w += (size_t)N * 4;
  int* bucket_count  = (int*)w; w += 1088;
  int* bucket_off    = (int*)w; w += 1088;
  int* bucket_cursor = (int*)w; w += 1088;
  int* flag     = (int*)w;    w += 64;
  float* pooled = (float*)w;  w += (size_t)NGRAPH * DIM * 4;
  int* pcnt     = (int*)w;    w += NGRAPH * 4;
  // staging overlays bufY+bufH (dead until gemm1, which runs after csr_build)
  int2* staging = (int2*)bufY;

  hipMemsetAsync(bucket_count, 0, 1088, stream);
  hipMemsetAsync(pooled, 0, (size_t)NGRAPH * DIM * 4 + NGRAPH * 4, stream);
  k_bucket_hist<<<1024, 256, 0, stream>>>(ei, E, bucket_count, NBUCK);
  k_bucket_scan<<<1, 256, 0, stream>>>(bucket_count, bucket_off, bucket_cursor,
                                       row_off, NBUCK, N, E);
  k_scatter<<<1024, 256, 0, stream>>>(ei, E, flag, bucket_cursor, staging, NBUCK);
  k_csr_build<<<NBUCK, 256, 0, stream>>>(staging, bucket_off, row_off, dinv, csr_src, N);

  int aggGrid = ((N + AGG_NODES - 1) / AGG_NODES) * 8;
  k_gemm_mfma<<<(N + 63) / 64, 256, 0, stream>>>(x, W1, dinv, bufY, N);
  k_aggregate<<<aggGrid, 256, 0, stream>>>(bufY, csr_src, row_off, dinv, b1, bufH, 1, N);
  k_gemm_mfma<<<(N + 63) / 64, 256, 0, stream>>>(bufH, W2, dinv, bufY, N);
  k_aggregate<<<aggGrid, 256, 0, stream>>>(bufY, csr_src, row_off, dinv, b2, bufH, 0, N);
  k_pool_partial<<<(N + 127) / 128, 128, 0, stream>>>(bufH, batch, pooled, pcnt, N, flag);
  k_final2<<<NGRAPH / 8, 256, 0, stream>>>(pooled, pcnt, Wl, bl, out);
}

// Round 8
// 427.303 us; speedup vs baseline: 1.1353x; 1.1353x over previous
//
#include <hip/hip_runtime.h>
#include <hip/hip_fp16.h>

#define DIM 128
#define NGRAPH 512
#define BUCKET_SHIFT 9
#define BUCKET_NODES 512

typedef _Float16 half8 __attribute__((ext_vector_type(8)));
typedef float floatx4 __attribute__((ext_vector_type(4)));

// ---------- per-block int64-layout detection ----------
__device__ __forceinline__ int detect64(const int* __restrict__ ei) {
  int all0 = 1;
#pragma unroll
  for (int k = 0; k < 32; ++k) all0 &= (ei[2 * k + 1] == 0);
  return all0;
}

__device__ __forceinline__ int edge_at(const int* p, long long idx, int is64) {
  return is64 ? p[idx * 2] : p[(size_t)idx];
}

// ---------- bucket histogram ----------
__global__ __launch_bounds__(256) void k_bucket_hist(const int* __restrict__ ei, int E,
                                                     int* __restrict__ bucket_count,
                                                     int nbuck) {
  __shared__ int h[256];
  int tid = threadIdx.x;
  h[tid] = 0;
  __syncthreads();
  int is64 = detect64(ei);
  int half = E >> 1;
  if (is64) {
    const int4* dp = (const int4*)(ei + 2 * (size_t)E);
    for (int t = blockIdx.x * 256 + tid; t < half; t += gridDim.x * 256) {
      int4 d = dp[t];
      atomicAdd(&h[d.x >> BUCKET_SHIFT], 1);
      atomicAdd(&h[d.z >> BUCKET_SHIFT], 1);
    }
  } else {
    const int2* dp = (const int2*)(ei + (size_t)E);
    for (int t = blockIdx.x * 256 + tid; t < half; t += gridDim.x * 256) {
      int2 d = dp[t];
      atomicAdd(&h[d.x >> BUCKET_SHIFT], 1);
      atomicAdd(&h[d.y >> BUCKET_SHIFT], 1);
    }
  }
  __syncthreads();
  if (tid < nbuck && h[tid]) atomicAdd(&bucket_count[tid], h[tid]);
  if ((E & 1) && blockIdx.x == 0 && tid == 0) {
    int d = edge_at(ei, (long long)E + (E - 1), is64);
    atomicAdd(&bucket_count[d >> BUCKET_SHIFT], 1);
  }
}

// ---------- scan buckets ----------
__global__ __launch_bounds__(256) void k_bucket_scan(const int* __restrict__ bucket_count,
                                                     int* __restrict__ bucket_off,
                                                     int* __restrict__ bucket_cursor,
                                                     int* __restrict__ row_off,
                                                     int nbuck, int N, int E) {
  __shared__ int s[256];
  int t = threadIdx.x;
  int v = (t < nbuck) ? bucket_count[t] : 0;
  s[t] = v;
  __syncthreads();
  for (int off = 1; off < 256; off <<= 1) {
    int u = (t >= off) ? s[t - off] : 0;
    __syncthreads();
    s[t] += u;
    __syncthreads();
  }
  int excl = s[t] - v;
  if (t < nbuck) { bucket_off[t] = excl; bucket_cursor[t] = excl; }
  if (t == 0) { bucket_off[nbuck] = E; row_off[N] = E; }
}

// ---------- scatter edges into bucket-grouped staging ----------
__global__ __launch_bounds__(256) void k_scatter(const int* __restrict__ ei, int E,
                                                 int* __restrict__ flag,
                                                 int* __restrict__ bucket_cursor,
                                                 int2* __restrict__ staging, int nbuck) {
  __shared__ int h[256];
  __shared__ int basebuf[256];
  int tid = threadIdx.x;
  int half = E >> 1;
  int ppb = (half + gridDim.x - 1) / gridDim.x;
  int lo = blockIdx.x * ppb;
  int hi = min(lo + ppb, half);
  h[tid] = 0;
  __syncthreads();
  int is64 = detect64(ei);
  if (blockIdx.x == 0 && tid == 0) *flag = is64;
  if (is64) {
    const int4* dp = (const int4*)(ei + 2 * (size_t)E);
    for (int t = lo + tid; t < hi; t += 256) {
      int4 d = dp[t];
      atomicAdd(&h[d.x >> BUCKET_SHIFT], 1);
      atomicAdd(&h[d.z >> BUCKET_SHIFT], 1);
    }
  } else {
    const int2* dp = (const int2*)(ei + (size_t)E);
    for (int t = lo + tid; t < hi; t += 256) {
      int2 d = dp[t];
      atomicAdd(&h[d.x >> BUCKET_SHIFT], 1);
      atomicAdd(&h[d.y >> BUCKET_SHIFT], 1);
    }
  }
  __syncthreads();
  if (tid < nbuck) {
    int c = h[tid];
    if (c) basebuf[tid] = atomicAdd(&bucket_cursor[tid], c);
    h[tid] = 0;
  }
  __syncthreads();
  if (is64) {
    const int4* sp = (const int4*)ei;
    const int4* dp = (const int4*)(ei + 2 * (size_t)E);
    for (int t = lo + tid; t < hi; t += 256) {
      int4 sv = sp[t];
      int4 dv = dp[t];
      int b0 = dv.x >> BUCKET_SHIFT;
      int l0 = atomicAdd(&h[b0], 1);
      staging[basebuf[b0] + l0] = make_int2(sv.x, dv.x);
      int b1 = dv.z >> BUCKET_SHIFT;
      int l1 = atomicAdd(&h[b1], 1);
      staging[basebuf[b1] + l1] = make_int2(sv.z, dv.z);
    }
  } else {
    const int2* sp = (const int2*)ei;
    const int2* dp = (const int2*)(ei + (size_t)E);
    for (int t = lo + tid; t < hi; t += 256) {
      int2 sv = sp[t];
      int2 dv = dp[t];
      int b0 = dv.x >> BUCKET_SHIFT;
      int l0 = atomicAdd(&h[b0], 1);
      staging[basebuf[b0] + l0] = make_int2(sv.x, dv.x);
      int b1 = dv.y >> BUCKET_SHIFT;
      int l1 = atomicAdd(&h[b1], 1);
      staging[basebuf[b1] + l1] = make_int2(sv.y, dv.y);
    }
  }
  if ((E & 1) && blockIdx.x == 0 && tid == 0) {
    int s0 = edge_at(ei, E - 1, is64);
    int d0 = edge_at(ei, (long long)E + (E - 1), is64);
    int pos = atomicAdd(&bucket_cursor[d0 >> BUCKET_SHIFT], 1);
    staging[pos] = make_int2(s0, d0);
  }
}

// ---------- per-bucket CSR build ----------
__global__ __launch_bounds__(256) void k_csr_build(const int2* __restrict__ staging,
                                                   const int* __restrict__ bucket_off,
                                                   int* __restrict__ row_off,
                                                   float* __restrict__ dinv,
                                                   int* __restrict__ csr_src, int N) {
  __shared__ int cnt_s[BUCKET_NODES];
  __shared__ int s[256];
  int tid = threadIdx.x;
  int b = blockIdx.x;
  int base = b << BUCKET_SHIFT;
  cnt_s[tid] = 0;
  cnt_s[tid + 256] = 0;
  __syncthreads();
  int start = bucket_off[b], end = bucket_off[b + 1];
  for (int i = start + tid; i < end; i += 256) {
    int2 e = staging[i];
    atomicAdd(&cnt_s[e.y - base], 1);
  }
  __syncthreads();
  int a0 = cnt_s[2 * tid], a1 = cnt_s[2 * tid + 1];
  int ps = a0 + a1;
  s[tid] = ps;
  __syncthreads();
  for (int off = 1; off < 256; off <<= 1) {
    int u = (tid >= off) ? s[tid - off] : 0;
    __syncthreads();
    s[tid] += u;
    __syncthreads();
  }
  int excl = s[tid] - ps;
  int r0 = start + excl;
  int r1 = r0 + a0;
  cnt_s[2 * tid] = r0;
  cnt_s[2 * tid + 1] = r1;
  int n0 = base + 2 * tid, n1 = n0 + 1;
  if (n0 < N) { row_off[n0] = r0; dinv[n0] = rsqrtf((float)(a0 + 1)); }
  if (n1 < N) { row_off[n1] = r1; dinv[n1] = rsqrtf((float)(a1 + 1)); }
  __syncthreads();
  for (int i = start + tid; i < end; i += 256) {
    int2 e = staging[i];
    int pos = atomicAdd(&cnt_s[e.y - base], 1);
    csr_src[pos] = e.x;
  }
}

// ---------- MFMA split-fp16 GEMM: Y = fp16( dinv .* (A @ W) ) ----------
// A16=0: A fp32, 3-term Ootomo (ah*bh + alo*bh + ah*bl), ~fp32-exact.
// A16=1: A fp16 exact, 2-term (ah*bh + ah*bl).
template <int A16>
__global__ __launch_bounds__(256) void k_gemm_mfma(
    const void* __restrict__ Av, const float* __restrict__ W,
    const float* __restrict__ dinv, __half* __restrict__ Y, int M) {
  __shared__ _Float16 WH[16384];          // [s][c][lane][8] : 32 KB
  __shared__ _Float16 WL[16384];          // residuals      : 32 KB
  __shared__ _Float16 OT[4][16 * 128];    // per-wave out tile: 16 KB
  int tid = threadIdx.x;

  for (int idx = tid; idx < 2048; idx += 256) {
    int l = idx & 63, c = (idx >> 6) & 7, s = idx >> 9;
    int kbase = s * 32 + ((l >> 4) << 3);
    int col = c * 16 + (l & 15);
#pragma unroll
    for (int j = 0; j < 8; ++j) {
      float w = W[(kbase + j) * 128 + col];
      _Float16 hh = (_Float16)w;
      WH[idx * 8 + j] = hh;
      WL[idx * 8 + j] = (_Float16)(w - (float)hh);
    }
  }
  __syncthreads();

  int wid = tid >> 6, l = tid & 63;
  int row0 = blockIdx.x * 64 + wid * 16;
  int arow = row0 + (l & 15);
  if (arow >= M) arow = M - 1;

  floatx4 acc[8];
#pragma unroll
  for (int c = 0; c < 8; ++c) acc[c] = (floatx4){0.f, 0.f, 0.f, 0.f};

#pragma unroll
  for (int s = 0; s < 4; ++s) {
    half8 ah, alo;
    if (A16) {
      const __half* A = (const __half*)Av;
      ah = *(const half8*)&A[(size_t)arow * 128 + s * 32 + ((l >> 4) << 3)];
    } else {
      const float* A = (const float*)Av;
      const float* ap = &A[(size_t)arow * 128 + s * 32 + ((l >> 4) << 3)];
      float4 f0 = *(const float4*)ap;
      float4 f1 = *(const float4*)(ap + 4);
      float fv[8] = {f0.x, f0.y, f0.z, f0.w, f1.x, f1.y, f1.z, f1.w};
#pragma unroll
      for (int j = 0; j < 8; ++j) {
        _Float16 hh = (_Float16)fv[j];
        ah[j] = hh;
        alo[j] = (_Float16)(fv[j] - (float)hh);
      }
    }
#pragma unroll
    for (int c = 0; c < 8; ++c) {
      int fi = ((s * 8 + c) * 64 + l) * 8;
      half8 bh = *(half8*)&WH[fi];
      half8 bl8 = *(half8*)&WL[fi];
      acc[c] = __builtin_amdgcn_mfma_f32_16x16x32_f16(ah, bh, acc[c], 0, 0, 0);
      if (!A16)
        acc[c] = __builtin_amdgcn_mfma_f32_16x16x32_f16(alo, bh, acc[c], 0, 0, 0);
      acc[c] = __builtin_amdgcn_mfma_f32_16x16x32_f16(ah, bl8, acc[c], 0, 0, 0);
    }
  }

  _Float16* ot = &OT[wid][0];
  int lrb = (l >> 4) * 4;
  float dv[4];
#pragma unroll
  for (int r = 0; r < 4; ++r) {
    int gr = row0 + lrb + r;
    dv[r] = (gr < M) ? dinv[gr] : 0.f;
  }
#pragma unroll
  for (int c = 0; c < 8; ++c)
#pragma unroll
    for (int r = 0; r < 4; ++r)
      ot[(lrb + r) * 128 + c * 16 + (l & 15)] = (_Float16)(acc[c][r] * dv[r]);
  const float4* otf = (const float4*)ot;
#pragma unroll
  for (int q = 0; q < 4; ++q) {
    int idx = q * 64 + l;
    int lrow = idx >> 4;
    int coff = (idx & 15) * 8;
    int grow = row0 + lrow;
    if (grow < M) *(float4*)&Y[(size_t)grow * 128 + coff] = otf[idx];
  }
}

// ---------- aggregation: wave = 1 node; lane-group g handles edge e+g ----------
// lane l: g=l>>4, q=l&15 -> loads 16 B (dims q*8..q*8+7) of edge e+g's row.
// Cross-group shfl_xor reduce at end. out fp16.
__global__ __launch_bounds__(256) void k_aggregate(
    const __half* __restrict__ y, const int* __restrict__ csr_src,
    const int* __restrict__ row_off, const float* __restrict__ dinv,
    const float* __restrict__ bias, __half* __restrict__ out16, int do_relu, int N) {
  __shared__ int sidx[1024];
  int tid = threadIdx.x;
  int n0 = blockIdx.x * 4;
  int blockBeg = row_off[n0];
  int blockEnd = row_off[min(n0 + 4, N)];
  int len = blockEnd - blockBeg;
  bool staged = (len <= 1024);
  int nload = staged ? len : 0;
  for (int t = tid; t < nload; t += 256) sidx[t] = csr_src[blockBeg + t];
  __syncthreads();

  int wave = tid >> 6, l = tid & 63;
  int node = n0 + wave;
  if (node >= N) return;
  int g = l >> 4, q = l & 15;
  int beg = row_off[node], end = row_off[node + 1];

  float a0 = 0.f, a1 = 0.f, a2 = 0.f, a3 = 0.f, a4 = 0.f, a5 = 0.f, a6 = 0.f, a7 = 0.f;
#define ACC8(F4)                                                        \
  {                                                                     \
    float4 _f = (F4);                                                   \
    __half2 _h0 = *(__half2*)&_f.x, _h1 = *(__half2*)&_f.y;             \
    __half2 _h2 = *(__half2*)&_f.z, _h3 = *(__half2*)&_f.w;             \
    a0 += __low2float(_h0); a1 += __high2float(_h0);                    \
    a2 += __low2float(_h1); a3 += __high2float(_h1);                    \
    a4 += __low2float(_h2); a5 += __high2float(_h2);                    \
    a6 += __low2float(_h3); a7 += __high2float(_h3);                    \
  }
  if (g == 0) ACC8(*(const float4*)&y[(size_t)node * 128 + q * 8]);  // self loop
  if (staged) {
    int rb = beg - blockBeg, re = end - blockBeg;
#pragma unroll 2
    for (int e = rb; e < re; e += 8) {
      int e0 = e + g, e1 = e + 4 + g;
      if (e0 < re) ACC8(*(const float4*)&y[(size_t)sidx[e0] * 128 + q * 8]);
      if (e1 < re) ACC8(*(const float4*)&y[(size_t)sidx[e1] * 128 + q * 8]);
    }
  } else {
    for (int e = beg; e < end; e += 8) {
      int e0 = e + g, e1 = e + 4 + g;
      if (e0 < end) ACC8(*(const float4*)&y[(size_t)csr_src[e0] * 128 + q * 8]);
      if (e1 < end) ACC8(*(const float4*)&y[(size_t)csr_src[e1] * 128 + q * 8]);
    }
  }
#undef ACC8
  // cross-group reduce (4 groups -> xor 16, 32)
  a0 += __shfl_xor(a0, 16); a1 += __shfl_xor(a1, 16);
  a2 += __shfl_xor(a2, 16); a3 += __shfl_xor(a3, 16);
  a4 += __shfl_xor(a4, 16); a5 += __shfl_xor(a5, 16);
  a6 += __shfl_xor(a6, 16); a7 += __shfl_xor(a7, 16);
  a0 += __shfl_xor(a0, 32); a1 += __shfl_xor(a1, 32);
  a2 += __shfl_xor(a2, 32); a3 += __shfl_xor(a3, 32);
  a4 += __shfl_xor(a4, 32); a5 += __shfl_xor(a5, 32);
  a6 += __shfl_xor(a6, 32); a7 += __shfl_xor(a7, 32);

  if (g == 0) {
    float di = dinv[node];
    const float* bp = &bias[q * 8];
    float r0 = di * a0 + bp[0], r1 = di * a1 + bp[1];
    float r2 = di * a2 + bp[2], r3 = di * a3 + bp[3];
    float r4 = di * a4 + bp[4], r5 = di * a5 + bp[5];
    float r6 = di * a6 + bp[6], r7 = di * a7 + bp[7];
    if (do_relu) {
      r0 = fmaxf(r0, 0.f); r1 = fmaxf(r1, 0.f); r2 = fmaxf(r2, 0.f);
      r3 = fmaxf(r3, 0.f); r4 = fmaxf(r4, 0.f); r5 = fmaxf(r5, 0.f);
      r6 = fmaxf(r6, 0.f); r7 = fmaxf(r7, 0.f);
    }
    __half2 h[4];
    h[0] = __floats2half2_rn(r0, r1);
    h[1] = __floats2half2_rn(r2, r3);
    h[2] = __floats2half2_rn(r4, r5);
    h[3] = __floats2half2_rn(r6, r7);
    *(float4*)&out16[(size_t)node * 128 + q * 8] = *(float4*)h;
  }
}

// ---------- parallel mean-pool partial (fp16 input) ----------
__global__ __launch_bounds__(128) void k_pool_partial(
    const __half* __restrict__ h, const int* __restrict__ batch,
    float* __restrict__ pooled, int* __restrict__ pcnt, int n,
    const int* __restrict__ flag) {
  __shared__ int sbatch[128];
  int tid = threadIdx.x;
  int n0 = blockIdx.x * 128;
  int n1 = min(n0 + 128, n);
  int cnt = n1 - n0;
  int is64 = *flag;
  if (tid < cnt) sbatch[tid] = is64 ? batch[2 * (n0 + tid)] : batch[n0 + tid];
  __syncthreads();
  float acc = 0.f;
  int gcur = sbatch[0];
  int runlen = 0;
  for (int r = 0; r < cnt; ++r) {
    int g = sbatch[r];
    if (g != gcur) {
      atomicAdd(&pooled[(size_t)gcur * 128 + tid], acc);
      if (tid == 0) atomicAdd(&pcnt[gcur], runlen);
      acc = 0.f; runlen = 0; gcur = g;
    }
    acc += __half2float(h[(size_t)(n0 + r) * 128 + tid]);
    ++runlen;
  }
  atomicAdd(&pooled[(size_t)gcur * 128 + tid], acc);
  if (tid == 0) atomicAdd(&pcnt[gcur], runlen);
}

// ---------- finish: mean + relu + [512x128]@[128x32] + bl ----------
__global__ __launch_bounds__(256) void k_final2(
    const float* __restrict__ pooled, const int* __restrict__ pcnt,
    const float* __restrict__ Wl, const float* __restrict__ bl,
    float* __restrict__ out) {
  __shared__ float sW[128 * 32];
  __shared__ float sg[8][128];
  int tid = threadIdx.x;
  for (int t = tid; t < 128 * 32; t += 256) sW[t] = Wl[t];
  int r = blockIdx.x * 8 + (tid >> 5);
  int c = tid & 31;
  float inv = 1.f / fmaxf((float)pcnt[r], 1.f);
#pragma unroll
  for (int q = 0; q < 4; ++q)
    sg[tid >> 5][c * 4 + q] = fmaxf(pooled[(size_t)r * 128 + c * 4 + q] * inv, 0.f);
  __syncthreads();
  const float* g = sg[tid >> 5];
  float acc = bl[c];
#pragma unroll 8
  for (int k = 0; k < 128; ++k) acc += g[k] * sW[k * 32 + c];
  out[r * 32 + c] = acc;
}

extern "C" void kernel_launch(void* const* d_in, const int* in_sizes, int n_in,
                              void* d_out, int out_size, void* d_ws, size_t ws_size,
                              hipStream_t stream) {
  const float* x   = (const float*)d_in[0];
  const int* ei    = (const int*)d_in[1];
  const int* batch = (const int*)d_in[2];
  const float* W1  = (const float*)d_in[3];
  const float* b1  = (const float*)d_in[4];
  const float* W2  = (const float*)d_in[5];
  const float* b2  = (const float*)d_in[6];
  const float* Wl  = (const float*)d_in[7];
  const float* bl  = (const float*)d_in[8];
  float* out = (float*)d_out;

  const int N = in_sizes[0] / DIM;   // 100000
  const int E = in_sizes[1] / 2;     // 1600000
  const int NBUCK = (N + BUCKET_NODES - 1) >> BUCKET_SHIFT;  // 196

  size_t need = (size_t)N * DIM * 2 + (size_t)N * DIM * 4 + (size_t)E * 4
              + (size_t)(N + 1) * 4 + (size_t)N * 4 + 3 * 1088 + 64
              + (size_t)NGRAPH * DIM * 4 + NGRAPH * 4;
  if (ws_size < need) return;

  char* w = (char*)d_ws;
  __half* bufY   = (__half*)w; w += (size_t)N * DIM * 2;  // gather payload
  __half* bufH16 = (__half*)w; w += (size_t)N * DIM * 4;  // h1 / h2 (fp16, room spare)
  int* csr_src  = (int*)w;    w += (size_t)E * 4;
  int* row_off  = (int*)w;    w += (size_t)(N + 1) * 4;
  float* dinv   = (float*)w;  w += (size_t)N * 4;
  int* bucket_count  = (int*)w; w += 1088;
  int* bucket_off    = (int*)w; w += 1088;
  int* bucket_cursor = (int*)w; w += 1088;
  int* flag     = (int*)w;    w += 64;
  float* pooled = (float*)w;  w += (size_t)NGRAPH * DIM * 4;
  int* pcnt     = (int*)w;    w += NGRAPH * 4;
  // staging overlays bufY (dead until gemm1, which runs after csr_build)
  int2* staging = (int2*)bufY;

  hipMemsetAsync(bucket_count, 0, 1088, stream);
  hipMemsetAsync(pooled, 0, (size_t)NGRAPH * DIM * 4 + NGRAPH * 4, stream);
  k_bucket_hist<<<1024, 256, 0, stream>>>(ei, E, bucket_count, NBUCK);
  k_bucket_scan<<<1, 256, 0, stream>>>(bucket_count, bucket_off, bucket_cursor,
                                       row_off, NBUCK, N, E);
  k_scatter<<<1024, 256, 0, stream>>>(ei, E, flag, bucket_cursor, staging, NBUCK);
  k_csr_build<<<NBUCK, 256, 0, stream>>>(staging, bucket_off, row_off, dinv, csr_src, N);

  k_gemm_mfma<0><<<(N + 63) / 64, 256, 0, stream>>>(x, W1, dinv, bufY, N);
  k_aggregate<<<(N + 3) / 4, 256, 0, stream>>>(bufY, csr_src, row_off, dinv, b1,
                                               bufH16, 1, N);
  k_gemm_mfma<1><<<(N + 63) / 64, 256, 0, stream>>>(bufH16, W2, dinv, bufY, N);
  k_aggregate<<<(N + 3) / 4, 256, 0, stream>>>(bufY, csr_src, row_off, dinv, b2,
                                               bufH16, 0, N);
  k_pool_partial<<<(N + 127) / 128, 128, 0, stream>>>(bufH16, batch, pooled, pcnt, N, flag);
  k_final2<<<NGRAPH / 8, 256, 0, stream>>>(pooled, pcnt, Wl, bl, out);
}